// Round 10
// baseline (261.060 us; speedup 1.0000x reference)
//
#include <hip/hip_runtime.h>
#include <cstdint>
#include <cstddef>

// fp32 I/O (verified r3). Internals: bf16 NHC activations + MFMA everywhere.
// mfma_f32_16x16x32_bf16 layouts (HW-verified m89/m120):
//   A: m=lane&15, k=quad*8+j   B: n=lane&15, k=quad*8+j
//   C/D: col(n)=lane&15, row(m)=quad*4+reg
// LDS tiles [row][64] bf16; XOR swizzle applied at the GLOBAL source chunk
// (sg = pg ^ (row&7)) so global_load_lds lands the swizzled image directly.
// *** global_load_lds RULE (m104/m108): LDS dest = wave-uniform base +
// lane*16 — every staging loop's dest offset MUST be linear in lane. ***
// r10 fix: r9's attn V-staging dest was pan*4096+d*64+pg*8 with pan from
// idx&15 -> NOT lane-linear -> HW scrambled the two key panels (r8/r9's
// 0.19-0.22 absmax). Re-decomposed as pan=idx>>9, d=(idx>>3)&63, pg=idx&7
// so dest = idx*16B exactly.
// Softmax: fixed-shift exp2 (exact by shift-invariance; |S| << 88 overflow),
// log2(e)/8 folded into Wq/bq. Split-K partials additive (no max state).

typedef __attribute__((ext_vector_type(8))) short short8;
typedef __attribute__((ext_vector_type(4))) float floatx4;

__device__ __forceinline__ unsigned short f2bf(float x) {
  union { float f; unsigned int u; } c; c.f = x;
  unsigned int r = c.u + 0x7FFFu + ((c.u >> 16) & 1u);   // RNE
  return (unsigned short)(r >> 16);
}
__device__ __forceinline__ float bf2f(unsigned short u) {
  union { unsigned int i; float f; } c; c.i = ((unsigned int)u) << 16; return c.f;
}
__device__ __forceinline__ void gload16(const void* g, void* l) {
  __builtin_amdgcn_global_load_lds(
      (const __attribute__((address_space(1))) unsigned int*)g,
      (__attribute__((address_space(3))) unsigned int*)l, 16, 0, 0);
}

#define LOG2E_8 0.18033688011112042f

// ---------------------------------------------------------------------------
// Transpose+convert both inputs: [b][c][n] fp32 -> [b][n][c] bf16.
// ---------------------------------------------------------------------------
__global__ __launch_bounds__(256) void tx_all(
    const float* __restrict__ x, const float* __restrict__ src,
    unsigned short* __restrict__ xb, unsigned short* __restrict__ sb,
    int C, int N)
{
  __shared__ float tile[32][33];
  const int which = blockIdx.z >> 1, b = blockIdx.z & 1;
  const float* X = which ? src : x;
  unsigned short* Y = which ? sb : xb;
  const int n0 = blockIdx.x * 32, c0 = blockIdx.y * 32;
  const int tc = threadIdx.x & 31, tr = threadIdx.x >> 5;
  #pragma unroll
  for (int i = 0; i < 4; ++i)
    tile[tr + i * 8][tc] = X[((size_t)b * C + c0 + tr + i * 8) * N + n0 + tc];
  __syncthreads();
  #pragma unroll
  for (int i = 0; i < 4; ++i)
    Y[((size_t)b * N + n0 + tr + i * 8) * C + c0 + tc] = f2bf(tile[tc][tr + i * 8]);
}

// ---------------------------------------------------------------------------
// All weight/bias prep in ONE dispatch (2568 blocks).
// ---------------------------------------------------------------------------
__global__ __launch_bounds__(256) void wprep(
    const float* __restrict__ Wq, const float* __restrict__ Wk,
    const float* __restrict__ Wv, const float* __restrict__ Wm,
    const float* __restrict__ W1, const float* __restrict__ W2,
    const float* __restrict__ bq, const float* __restrict__ bk,
    const float* __restrict__ bv, const float* __restrict__ bm,
    const float* __restrict__ b1, const float* __restrict__ b2,
    unsigned short* __restrict__ wqkv, unsigned short* __restrict__ wmb,
    unsigned short* __restrict__ w1b, unsigned short* __restrict__ w2b,
    float* __restrict__ biasb, float* __restrict__ Pzero)
{
  const int bid = blockIdx.x, t = threadIdx.x;
  if (bid < 768) {
    const int idx = bid * 256 + t;
    const int op = idx >> 8, ip = idx & 255;
    const int grp = op >> 8, oo = op & 255;
    const int o = 4 * (oo & 63) + (oo >> 6);
    const float* W = grp == 0 ? Wq : grp == 1 ? Wk : Wv;
    const float sc = grp == 0 ? LOG2E_8 : 1.f;
    wqkv[idx] = f2bf(W[(size_t)o * 256 + ip] * sc);
  } else if (bid < 1024) {
    const int idx = (bid - 768) * 256 + t;
    const int o = idx >> 8, ip = idx & 255;
    const int i2 = 4 * (ip & 63) + (ip >> 6);
    wmb[idx] = f2bf(Wm[(size_t)o * 256 + i2]);
  } else if (bid < 2048) {
    const int idx = (bid - 1024) * 256 + t;
    w1b[idx] = f2bf(W1[idx]);
  } else if (bid < 2560) {
    const int idx = (bid - 2048) * 256 + t;
    w2b[idx] = f2bf(W2[idx]);
  } else if (bid < 2567) {
    const int z = (bid - 2560) * 256 + t;
    if (z < 256)       biasb[z] = bq[4 * (z & 63) + (z >> 6)] * LOG2E_8;
    else if (z < 512)  { const int y = z - 256; biasb[z] = bk[4 * (y & 63) + (y >> 6)]; }
    else if (z < 768)  { const int y = z - 512; biasb[z] = bv[4 * (y & 63) + (y >> 6)]; }
    else if (z < 1024) biasb[z] = bm[z - 768];
    else if (z < 1536) biasb[z] = b1[z - 1024];
    else if (z < 1792) biasb[z] = b2[z - 1536];
  } else {
    #pragma unroll
    for (int k = 0; k < 8; ++k) Pzero[k * 256 + t] = 0.f;
  }
}

// ---------------------------------------------------------------------------
// 128x128-tile MFMA GEMM, global_load_lds staging (dest linear in lane).
// variant 0: NHC bf16 out O0
// variant 1: fused qkv (q->O0, k->O1 NHC 256; v->O2 [b][h][d][n])
// variant 2: CHN fp32 out O0
// variant 4: NHC bf16 out O0 + fp32 stats atomics into Ps/Ps2 (per channel o)
// ---------------------------------------------------------------------------
__global__ __launch_bounds__(256) void gemm128(
    const unsigned short* __restrict__ Wb, const float* __restrict__ bias,
    const unsigned short* __restrict__ X0, const unsigned short* __restrict__ X1,
    void* __restrict__ O0, void* __restrict__ O1, void* __restrict__ O2,
    int Co, int Ci, int Ci0, int N, int variant,
    float* __restrict__ Ps, float* __restrict__ Ps2)
{
  const int n0 = blockIdx.x * 128;
  const int o0 = blockIdx.y * 128;
  const int b  = blockIdx.z;
  const int t  = threadIdx.x;
  const int w = t >> 6, lane = t & 63, qd = lane >> 4, l = lane & 15;
  const int oh = (w >> 1) * 64, nh = (w & 1) * 64;

  __shared__ unsigned short Wl[128 * 64];
  __shared__ unsigned short Xl[128 * 64];

  floatx4 acc[4][4];
  #pragma unroll
  for (int i = 0; i < 4; ++i)
    #pragma unroll
    for (int j = 0; j < 4; ++j) acc[i][j] = (floatx4){0.f, 0.f, 0.f, 0.f};

  for (int k0 = 0; k0 < Ci; k0 += 64) {
    const unsigned short* Xs; int cb, rl;
    if (variant == 1) { Xs = (o0 < 256) ? X0 : X1; cb = k0; rl = Ci; }
    else if (k0 < Ci0) { Xs = X0; cb = k0; rl = Ci0; }
    else               { Xs = X1; cb = k0 - Ci0; rl = Ci - Ci0; }
    __syncthreads();
    #pragma unroll
    for (int i = 0; i < 4; ++i) {
      const int idx = i * 256 + t;
      const int row = idx >> 3, pg = idx & 7, sg = pg ^ (row & 7);
      gload16(&Wb[(size_t)(o0 + row) * Ci + k0 + sg * 8], &Wl[row * 64 + pg * 8]);
      gload16(&Xs[((size_t)b * N + n0 + row) * rl + cb + sg * 8], &Xl[row * 64 + pg * 8]);
    }
    __syncthreads();

    short8 af[4][2], bf[4][2];
    #pragma unroll
    for (int i = 0; i < 4; ++i) {
      const int ar = oh + 16 * i + l;
      af[i][0] = *(const short8*)&Wl[ar * 64 + ((qd ^ (ar & 7))) * 8];
      af[i][1] = *(const short8*)&Wl[ar * 64 + (((4 + qd) ^ (ar & 7))) * 8];
    }
    #pragma unroll
    for (int j = 0; j < 4; ++j) {
      const int br = nh + 16 * j + l;
      bf[j][0] = *(const short8*)&Xl[br * 64 + ((qd ^ (br & 7))) * 8];
      bf[j][1] = *(const short8*)&Xl[br * 64 + (((4 + qd) ^ (br & 7))) * 8];
    }
    #pragma unroll
    for (int i = 0; i < 4; ++i)
      #pragma unroll
      for (int j = 0; j < 4; ++j) {
        acc[i][j] = __builtin_amdgcn_mfma_f32_16x16x32_bf16(af[i][0], bf[j][0], acc[i][j], 0, 0, 0);
        acc[i][j] = __builtin_amdgcn_mfma_f32_16x16x32_bf16(af[i][1], bf[j][1], acc[i][j], 0, 0, 0);
      }
  }

  const int osec = o0 + oh;
  if (variant == 4) {
    unsigned short* C = (unsigned short*)O0;
    float s1[4][4], s2[4][4];
    #pragma unroll
    for (int i = 0; i < 4; ++i) {
      const int o4 = o0 + oh + 16 * i + qd * 4;
      const float4 bi = *(const float4*)&bias[o4];
      #pragma unroll
      for (int rg = 0; rg < 4; ++rg) { s1[i][rg] = 0.f; s2[i][rg] = 0.f; }
      #pragma unroll
      for (int j = 0; j < 4; ++j) {
        const int n = n0 + nh + 16 * j + l;
        float v[4];
        v[0] = acc[i][j][0] + bi.x; v[1] = acc[i][j][1] + bi.y;
        v[2] = acc[i][j][2] + bi.z; v[3] = acc[i][j][3] + bi.w;
        ushort4 pk;
        pk.x = f2bf(v[0]); pk.y = f2bf(v[1]); pk.z = f2bf(v[2]); pk.w = f2bf(v[3]);
        *(ushort4*)&C[((size_t)b * N + n) * Co + o4] = pk;
        #pragma unroll
        for (int rg = 0; rg < 4; ++rg) {
          s1[i][rg] += v[rg];
          s2[i][rg] += v[rg] * v[rg];
        }
      }
    }
    #pragma unroll
    for (int i = 0; i < 4; ++i)
      #pragma unroll
      for (int rg = 0; rg < 4; ++rg) {
        float a = s1[i][rg], c2 = s2[i][rg];
        a  += __shfl_xor(a, 1);  c2 += __shfl_xor(c2, 1);
        a  += __shfl_xor(a, 2);  c2 += __shfl_xor(c2, 2);
        a  += __shfl_xor(a, 4);  c2 += __shfl_xor(c2, 4);
        a  += __shfl_xor(a, 8);  c2 += __shfl_xor(c2, 8);
        if (l == 0) {
          const int o = o0 + oh + 16 * i + qd * 4 + rg;
          atomicAdd(&Ps [b * 512 + o], a);
          atomicAdd(&Ps2[b * 512 + o], c2);
        }
      }
    return;
  }

  #pragma unroll
  for (int i = 0; i < 4; ++i) {
    const int o4 = o0 + oh + 16 * i + qd * 4;
    const float4 bi = *(const float4*)&bias[o4];
    #pragma unroll
    for (int j = 0; j < 4; ++j) {
      const int n = n0 + nh + 16 * j + l;
      if (variant == 0) {
        unsigned short* C = (unsigned short*)O0;
        ushort4 pk;
        pk.x = f2bf(acc[i][j][0] + bi.x); pk.y = f2bf(acc[i][j][1] + bi.y);
        pk.z = f2bf(acc[i][j][2] + bi.z); pk.w = f2bf(acc[i][j][3] + bi.w);
        *(ushort4*)&C[((size_t)b * N + n) * Co + o4] = pk;
      } else if (variant == 1) {
        if (osec < 256) {
          unsigned short* C = (unsigned short*)O0;
          ushort4 pk;
          pk.x = f2bf(acc[i][j][0] + bi.x); pk.y = f2bf(acc[i][j][1] + bi.y);
          pk.z = f2bf(acc[i][j][2] + bi.z); pk.w = f2bf(acc[i][j][3] + bi.w);
          *(ushort4*)&C[((size_t)b * N + n) * 256 + o4] = pk;
        } else if (osec < 512) {
          unsigned short* C = (unsigned short*)O1;
          ushort4 pk;
          pk.x = f2bf(acc[i][j][0] + bi.x); pk.y = f2bf(acc[i][j][1] + bi.y);
          pk.z = f2bf(acc[i][j][2] + bi.z); pk.w = f2bf(acc[i][j][3] + bi.w);
          *(ushort4*)&C[((size_t)b * N + n) * 256 + (o4 - 256)] = pk;
        } else {
          unsigned short* C = (unsigned short*)O2;
          #pragma unroll
          for (int rg = 0; rg < 4; ++rg) {
            const int op = o4 - 512 + rg, h = op >> 6, d = op & 63;
            C[(((size_t)b * 4 + h) * 64 + d) * N + n] =
                f2bf(acc[i][j][rg] + ((const float*)&bi)[rg]);
          }
        }
      } else {
        float* C = (float*)O0;
        #pragma unroll
        for (int rg = 0; rg < 4; ++rg)
          C[((size_t)b * Co + o4 + rg) * N + n] = acc[i][j][rg] + ((const float*)&bi)[rg];
      }
    }
  }
}

// ---------------------------------------------------------------------------
// MFMA flash attention, split-K x4, 128 q/block, 128-key tiles (2 x 64 panels).
// V-staging dest index FIXED to be lane-linear (pan = idx>>9).
// Grid (N/128, H, B*4).
// ---------------------------------------------------------------------------
__global__ __launch_bounds__(256) void attn_mfma(
    const unsigned short* __restrict__ qb, const unsigned short* __restrict__ kb,
    const unsigned short* __restrict__ vh, unsigned short* __restrict__ Opart,
    float* __restrict__ liPart, int N)
{
  const int qt = blockIdx.x;
  const int h  = blockIdx.y;
  const int b  = blockIdx.z >> 2, s = blockIdx.z & 3;
  const int n0 = qt * 128;
  const int t  = threadIdx.x;
  const int w = t >> 6, lane = t & 63, qd = lane >> 4, l = lane & 15;

  __shared__ unsigned short Kl[2][64 * 64];   // [panel][key][d] swizzled
  __shared__ unsigned short Vl[2][64 * 64];   // [panel][d][key] swizzled
  __shared__ unsigned short Pl[4][16 * 64];   // wave-private [q][key-in-panel]

  const unsigned short* qp0 = &qb[((size_t)b * N + n0 + 16 * w + l) * 256 + h * 64];
  const unsigned short* qp1 = qp0 + (size_t)64 * 256;
  short8 aQ[2][2];
  aQ[0][0] = *(const short8*)&qp0[qd * 8];
  aQ[0][1] = *(const short8*)&qp0[32 + qd * 8];
  aQ[1][0] = *(const short8*)&qp1[qd * 8];
  aQ[1][1] = *(const short8*)&qp1[32 + qd * 8];

  floatx4 accO[2][4];
  #pragma unroll
  for (int qs = 0; qs < 2; ++qs)
    #pragma unroll
    for (int ds = 0; ds < 4; ++ds) accO[qs][ds] = (floatx4){0.f, 0.f, 0.f, 0.f};
  float li[2][4] = {};

  const int j0base = s * 1024;
  for (int jt = 0; jt < 8; ++jt) {
    const int j0 = j0base + jt * 128;
    __syncthreads();
    #pragma unroll
    for (int i = 0; i < 4; ++i) {
      const int idx = i * 256 + t;
      {
        // K: dest = idx*16B (lane-linear). row = key 0..127.
        const int row = idx >> 3, pg = idx & 7, sg = pg ^ (row & 7);
        gload16(&kb[((size_t)b * N + j0 + row) * 256 + h * 64 + sg * 8],
                &Kl[row >> 6][(row & 63) * 64 + pg * 8]);
      }
      {
        // V: dest = idx*16B (lane-linear). pan=idx>>9, d=(idx>>3)&63, pg=idx&7.
        const int pan = idx >> 9, d = (idx >> 3) & 63, pg = idx & 7;
        const int sg = pg ^ (d & 7);
        gload16(&vh[(((size_t)b * 4 + h) * 64 + d) * N + j0 + pan * 64 + sg * 8],
                &Vl[pan][d * 64 + pg * 8]);
      }
    }
    __syncthreads();

    #pragma unroll
    for (int p = 0; p < 2; ++p) {
      short8 kf[4][2], vf[4][2];
      #pragma unroll
      for (int js = 0; js < 4; ++js) {
        const int br = 16 * js + l;
        kf[js][0] = *(const short8*)&Kl[p][br * 64 + ((qd ^ (br & 7))) * 8];
        kf[js][1] = *(const short8*)&Kl[p][br * 64 + (((4 + qd) ^ (br & 7))) * 8];
        vf[js][0] = *(const short8*)&Vl[p][br * 64 + ((qd ^ (br & 7))) * 8];
        vf[js][1] = *(const short8*)&Vl[p][br * 64 + (((4 + qd) ^ (br & 7))) * 8];
      }
      #pragma unroll
      for (int qs = 0; qs < 2; ++qs) {
        floatx4 S[4];
        #pragma unroll
        for (int js = 0; js < 4; ++js) {
          floatx4 a = (floatx4){0.f, 0.f, 0.f, 0.f};
          a = __builtin_amdgcn_mfma_f32_16x16x32_bf16(aQ[qs][0], kf[js][0], a, 0, 0, 0);
          a = __builtin_amdgcn_mfma_f32_16x16x32_bf16(aQ[qs][1], kf[js][1], a, 0, 0, 0);
          S[js] = a;
        }
        #pragma unroll
        for (int js = 0; js < 4; ++js) {
          const int kg = 2 * js + (l >> 3);
          #pragma unroll
          for (int rg = 0; rg < 4; ++rg) {
            const float pv = __builtin_exp2f(S[js][rg]);
            li[qs][rg] += pv;
            union { float f; unsigned int u; } cv; cv.f = pv;
            const int qr = qd * 4 + rg;
            Pl[w][qr * 64 + ((kg ^ (qr & 7))) * 8 + (l & 7)] =
                (unsigned short)((cv.u + 0x8000u) >> 16);
          }
        }
        const short8 aP0 = *(const short8*)&Pl[w][l * 64 + ((qd ^ (l & 7))) * 8];
        const short8 aP1 = *(const short8*)&Pl[w][l * 64 + (((4 + qd) ^ (l & 7))) * 8];
        #pragma unroll
        for (int ds = 0; ds < 4; ++ds) {
          accO[qs][ds] = __builtin_amdgcn_mfma_f32_16x16x32_bf16(aP0, vf[ds][0], accO[qs][ds], 0, 0, 0);
          accO[qs][ds] = __builtin_amdgcn_mfma_f32_16x16x32_bf16(aP1, vf[ds][1], accO[qs][ds], 0, 0, 0);
        }
      }
    }
  }

  const size_t obase = ((((size_t)b * 4 + h) * 4 + s) * 32 + qt) * 128;
  #pragma unroll
  for (int qs = 0; qs < 2; ++qs)
    #pragma unroll
    for (int rg = 0; rg < 4; ++rg) {
      float sum = li[qs][rg];
      sum += __shfl_xor(sum, 1);
      sum += __shfl_xor(sum, 2);
      sum += __shfl_xor(sum, 4);
      sum += __shfl_xor(sum, 8);
      const int q = qs * 64 + 16 * w + qd * 4 + rg;
      #pragma unroll
      for (int ds = 0; ds < 4; ++ds)
        Opart[(obase + q) * 64 + 16 * ds + l] = f2bf(accO[qs][ds][rg]);
      if (l == 0) liPart[obase + q] = sum;
    }
}

// ---------------------------------------------------------------------------
// Combine 4 split-K partials -> atb NHC head-major bf16. Grid (N/128, H, B).
// ---------------------------------------------------------------------------
__global__ __launch_bounds__(256) void attn_combine(
    const unsigned short* __restrict__ Opart, const float* __restrict__ liPart,
    unsigned short* __restrict__ atb, int N)
{
  const int qt = blockIdx.x, h = blockIdx.y, b = blockIdx.z;
  const int t = threadIdx.x;
  const int q = t >> 1, d0 = (t & 1) * 32;

  float li = 0.f;
  size_t idx[4];
  #pragma unroll
  for (int s = 0; s < 4; ++s) {
    idx[s] = ((((size_t)b * 4 + h) * 4 + s) * 32 + qt) * 128 + q;
    li += liPart[idx[s]];
  }
  const float inv = 1.f / li;

  float o[32];
  #pragma unroll
  for (int c = 0; c < 32; ++c) o[c] = 0.f;
  #pragma unroll
  for (int s = 0; s < 4; ++s) {
    #pragma unroll
    for (int c4 = 0; c4 < 4; ++c4) {
      const short8 v = *(const short8*)&Opart[idx[s] * 64 + d0 + c4 * 8];
      #pragma unroll
      for (int j = 0; j < 8; ++j) o[c4 * 8 + j] += bf2f((unsigned short)v[j]);
    }
  }
  unsigned short* dst = &atb[((size_t)b * N + qt * 128 + q) * 256 + h * 64 + d0];
  #pragma unroll
  for (int c4 = 0; c4 < 4; ++c4) {
    ushort4 pk;
    pk.x = f2bf(o[c4 * 8 + 0] * inv); pk.y = f2bf(o[c4 * 8 + 1] * inv);
    pk.z = f2bf(o[c4 * 8 + 2] * inv); pk.w = f2bf(o[c4 * 8 + 3] * inv);
    *(ushort4*)&dst[c4 * 8] = pk;
    pk.x = f2bf(o[c4 * 8 + 4] * inv); pk.y = f2bf(o[c4 * 8 + 5] * inv);
    pk.z = f2bf(o[c4 * 8 + 6] * inv); pk.w = f2bf(o[c4 * 8 + 7] * inv);
    *(ushort4*)&dst[c4 * 8 + 4] = pk;
  }
}

// ---------------------------------------------------------------------------
// InstanceNorm finalize+normalize from fused stats. Grid (8, 16, B).
// ---------------------------------------------------------------------------
__global__ __launch_bounds__(256) void in_norm(
    unsigned short* __restrict__ H, const float* __restrict__ Ps,
    const float* __restrict__ Ps2, int N)
{
  const int cg = blockIdx.x, ns = blockIdx.y, b = blockIdx.z, t = threadIdx.x;
  __shared__ float muS[64], ivS[64];
  if (t < 64) {
    const int c = cg * 64 + t;
    const float mu = Ps[b * 512 + c] / (float)N;
    const float var = fmaxf(Ps2[b * 512 + c] / (float)N - mu * mu, 0.f);
    muS[t] = mu;
    ivS[t] = rsqrtf(var + 1e-5f);
  }
  __syncthreads();
  const int c0 = cg * 64 + (t & 7) * 8;
  float mu[8], iv[8];
  #pragma unroll
  for (int j = 0; j < 8; ++j) {
    mu[j] = muS[(t & 7) * 8 + j];
    iv[j] = ivS[(t & 7) * 8 + j];
  }
  #pragma unroll
  for (int i = 0; i < 8; ++i) {
    const int n = ns * 256 + (t >> 3) + i * 32;
    unsigned short* p = &H[((size_t)b * N + n) * 512 + c0];
    short8 hv = *(const short8*)p;
    #pragma unroll
    for (int j = 0; j < 8; ++j) {
      const float f = fmaxf((bf2f((unsigned short)hv[j]) - mu[j]) * iv[j], 0.f);
      hv[j] = (short)f2bf(f);
    }
    *(short8*)p = hv;
  }
}

// ---------------------------------------------------------------------------
extern "C" void kernel_launch(void* const* d_in, const int* in_sizes, int n_in,
                              void* d_out, int out_size, void* d_ws, size_t ws_size,
                              hipStream_t stream)
{
  const int B = 2, D = 256, N = 4096;

  const float* x   = (const float*)d_in[0];
  const float* src = (const float*)d_in[1];
  const float* Wq  = (const float*)d_in[2];  const float* bq = (const float*)d_in[3];
  const float* Wk  = (const float*)d_in[4];  const float* bk = (const float*)d_in[5];
  const float* Wv  = (const float*)d_in[6];  const float* bv = (const float*)d_in[7];
  const float* Wm  = (const float*)d_in[8];  const float* bm = (const float*)d_in[9];
  const float* W1  = (const float*)d_in[10]; const float* b1 = (const float*)d_in[11];
  const float* W2  = (const float*)d_in[12]; const float* b2 = (const float*)d_in[13];
  float* out = (float*)d_out;

  char* ws = (char*)d_ws;
  const size_t MB = 1u << 20;
  unsigned short* xb  = (unsigned short*)(ws + 0 * MB);
  unsigned short* sb  = (unsigned short*)(ws + 4 * MB);
  unsigned short* qbf = (unsigned short*)(ws + 8 * MB);
  unsigned short* kbf = (unsigned short*)(ws + 12 * MB);
  unsigned short* vhb = (unsigned short*)(ws + 16 * MB);
  unsigned short* atb = (unsigned short*)(ws + 20 * MB);
  unsigned short* Opart = (unsigned short*)(ws + 24 * MB);  // dead after combine
  unsigned short* msb = (unsigned short*)(ws + 24 * MB);    // NHC 256 (post-combine)
  unsigned short* hb  = (unsigned short*)(ws + 28 * MB);    // [b][n][512]
  float* liPart = (float*)(ws + 41 * MB);
  unsigned short* wqkvb = (unsigned short*)(ws + 42 * MB);  // [768][256]
  unsigned short* wmb = wqkvb + 768 * 256;                  // [256][256]
  unsigned short* w1b = wmb + 256 * 256;                    // [512][512]
  unsigned short* w2b = w1b + 512 * 512;                    // [256][512]
  float* biasb = (float*)(ws + 44 * MB);                    // 1792 used
  float* Ps    = biasb + 2048;                              // 1024
  float* Ps2   = Ps + 1024;                                 // 1024

  const dim3 blk(256);

  tx_all<<<dim3(N / 32, D / 32, 2 * B), blk, 0, stream>>>(x, src, xb, sb, D, N);
  wprep<<<dim3(2568), blk, 0, stream>>>(Wq, Wk, Wv, Wm, W1, W2,
                                        bq, bk, bv, bm, b1, b2,
                                        wqkvb, wmb, w1b, w2b, biasb, Ps);

  // fused q/k/v
  gemm128<<<dim3(N / 128, 6, B), blk, 0, stream>>>(
      wqkvb, biasb, xb, sb, qbf, kbf, vhb, 768, 256, 256, N, 1, nullptr, nullptr);

  attn_mfma<<<dim3(N / 128, 4, B * 4), blk, 0, stream>>>(
      qbf, kbf, vhb, Opart, liPart, N);
  attn_combine<<<dim3(N / 128, 4, B), blk, 0, stream>>>(Opart, liPart, atb, N);

  // message (cols head-major-permuted to match atb)
  gemm128<<<dim3(N / 128, 2, B), blk, 0, stream>>>(
      wmb, biasb + 768, atb, atb, msb, nullptr, nullptr, 256, 256, 256, N, 0,
      nullptr, nullptr);

  // h = W1 @ [x; msg] + b1, with fused InstanceNorm stats (variant 4)
  gemm128<<<dim3(N / 128, 4, B), blk, 0, stream>>>(
      w1b, biasb + 1024, xb, msb, hb, nullptr, nullptr,
      512, 512, 256, N, 4, Ps, Ps2);

  in_norm<<<dim3(8, 16, B), blk, 0, stream>>>(hb, Ps, Ps2, N);

  // out = W2 @ h (fp32 CHN)
  gemm128<<<dim3(N / 128, 2, B), blk, 0, stream>>>(
      w2b, biasb + 1536, hb, hb, out, nullptr, nullptr,
      256, 512, 512, N, 2, nullptr, nullptr);
}

// Round 11
// 238.417 us; speedup vs baseline: 1.0950x; 1.0950x over previous
//
#include <hip/hip_runtime.h>
#include <cstdint>
#include <cstddef>

// fp32 I/O (verified r3). Internals: bf16 NHC activations + MFMA everywhere.
// mfma_f32_16x16x32_bf16 layouts (HW-verified m89/m120):
//   A: m=lane&15, k=quad*8+j   B: n=lane&15, k=quad*8+j
//   C/D: col(n)=lane&15, row(m)=quad*4+reg
// LDS tiles [row][64] bf16; XOR swizzle applied at the GLOBAL source chunk
// (sg = pg ^ (row&7)) so global_load_lds lands the swizzled image directly.
// *** global_load_lds RULE (m104/m108): LDS dest = wave-uniform base +
// lane*16 — every staging dest offset MUST be linear in lane (= idx*16B). ***
// Softmax: fixed-shift exp2 (exact by shift-invariance; |S| << 88 overflow),
// log2(e)/8 folded into Wq/bq. Split-K partials additive (no max state).
// r11: attention reverted to r7's proven 64-key-tile kernel (24KB LDS; the
// r10 128-key panel variant cost occupancy 18.8->11% and +35us). GEMMs moved
// to 64x64 tiles (r5-proven mapping): grids are tiny (128-384 blocks at
// 128-tile), latency-bound -> 4x more blocks beats LDS-ratio arguments here.

typedef __attribute__((ext_vector_type(8))) short short8;
typedef __attribute__((ext_vector_type(4))) float floatx4;

__device__ __forceinline__ unsigned short f2bf(float x) {
  union { float f; unsigned int u; } c; c.f = x;
  unsigned int r = c.u + 0x7FFFu + ((c.u >> 16) & 1u);   // RNE
  return (unsigned short)(r >> 16);
}
__device__ __forceinline__ float bf2f(unsigned short u) {
  union { unsigned int i; float f; } c; c.i = ((unsigned int)u) << 16; return c.f;
}
__device__ __forceinline__ void gload16(const void* g, void* l) {
  __builtin_amdgcn_global_load_lds(
      (const __attribute__((address_space(1))) unsigned int*)g,
      (__attribute__((address_space(3))) unsigned int*)l, 16, 0, 0);
}

#define LOG2E_8 0.18033688011112042f

// ---------------------------------------------------------------------------
// Transpose+convert both inputs: [b][c][n] fp32 -> [b][n][c] bf16.
// ---------------------------------------------------------------------------
__global__ __launch_bounds__(256) void tx_all(
    const float* __restrict__ x, const float* __restrict__ src,
    unsigned short* __restrict__ xb, unsigned short* __restrict__ sb,
    int C, int N)
{
  __shared__ float tile[32][33];
  const int which = blockIdx.z >> 1, b = blockIdx.z & 1;
  const float* X = which ? src : x;
  unsigned short* Y = which ? sb : xb;
  const int n0 = blockIdx.x * 32, c0 = blockIdx.y * 32;
  const int tc = threadIdx.x & 31, tr = threadIdx.x >> 5;
  #pragma unroll
  for (int i = 0; i < 4; ++i)
    tile[tr + i * 8][tc] = X[((size_t)b * C + c0 + tr + i * 8) * N + n0 + tc];
  __syncthreads();
  #pragma unroll
  for (int i = 0; i < 4; ++i)
    Y[((size_t)b * N + n0 + tr + i * 8) * C + c0 + tc] = f2bf(tile[tc][tr + i * 8]);
}

// ---------------------------------------------------------------------------
// All weight/bias prep in ONE dispatch (2568 blocks).
// ---------------------------------------------------------------------------
__global__ __launch_bounds__(256) void wprep(
    const float* __restrict__ Wq, const float* __restrict__ Wk,
    const float* __restrict__ Wv, const float* __restrict__ Wm,
    const float* __restrict__ W1, const float* __restrict__ W2,
    const float* __restrict__ bq, const float* __restrict__ bk,
    const float* __restrict__ bv, const float* __restrict__ bm,
    const float* __restrict__ b1, const float* __restrict__ b2,
    unsigned short* __restrict__ wqkv, unsigned short* __restrict__ wmb,
    unsigned short* __restrict__ w1b, unsigned short* __restrict__ w2b,
    float* __restrict__ biasb, float* __restrict__ Pzero)
{
  const int bid = blockIdx.x, t = threadIdx.x;
  if (bid < 768) {
    const int idx = bid * 256 + t;
    const int op = idx >> 8, ip = idx & 255;
    const int grp = op >> 8, oo = op & 255;
    const int o = 4 * (oo & 63) + (oo >> 6);
    const float* W = grp == 0 ? Wq : grp == 1 ? Wk : Wv;
    const float sc = grp == 0 ? LOG2E_8 : 1.f;
    wqkv[idx] = f2bf(W[(size_t)o * 256 + ip] * sc);
  } else if (bid < 1024) {
    const int idx = (bid - 768) * 256 + t;
    const int o = idx >> 8, ip = idx & 255;
    const int i2 = 4 * (ip & 63) + (ip >> 6);
    wmb[idx] = f2bf(Wm[(size_t)o * 256 + i2]);
  } else if (bid < 2048) {
    const int idx = (bid - 1024) * 256 + t;
    w1b[idx] = f2bf(W1[idx]);
  } else if (bid < 2560) {
    const int idx = (bid - 2048) * 256 + t;
    w2b[idx] = f2bf(W2[idx]);
  } else if (bid < 2567) {
    const int z = (bid - 2560) * 256 + t;
    if (z < 256)       biasb[z] = bq[4 * (z & 63) + (z >> 6)] * LOG2E_8;
    else if (z < 512)  { const int y = z - 256; biasb[z] = bk[4 * (y & 63) + (y >> 6)]; }
    else if (z < 768)  { const int y = z - 512; biasb[z] = bv[4 * (y & 63) + (y >> 6)]; }
    else if (z < 1024) biasb[z] = bm[z - 768];
    else if (z < 1536) biasb[z] = b1[z - 1024];
    else if (z < 1792) biasb[z] = b2[z - 1536];
  } else {
    #pragma unroll
    for (int k = 0; k < 8; ++k) Pzero[k * 256 + t] = 0.f;
  }
}

// ---------------------------------------------------------------------------
// 64x64-tile MFMA GEMM, global_load_lds staging (dest = idx*16B, lane-linear).
// C[b,o,n] = sum_i W[o,i]*X[b,n,i] + bias[o]. Grid (N/64, Co/64, B).
// Wave w owns o rows 16w..16w+15 of the tile, all 64 n (4 ns frags).
// variant 0: NHC bf16 out O0
// variant 1: fused qkv (o0<256 -> O0 q; <512 -> O1 k; else O2 v [b][h][d][n])
// variant 2: CHN fp32 out O0
// variant 4: NHC bf16 out O0 + fp32 stats atomics into Ps/Ps2 (per channel o)
// ---------------------------------------------------------------------------
__global__ __launch_bounds__(256) void gemm64(
    const unsigned short* __restrict__ Wb, const float* __restrict__ bias,
    const unsigned short* __restrict__ X0, const unsigned short* __restrict__ X1,
    void* __restrict__ O0, void* __restrict__ O1, void* __restrict__ O2,
    int Co, int Ci, int Ci0, int N, int variant,
    float* __restrict__ Ps, float* __restrict__ Ps2)
{
  const int n0 = blockIdx.x * 64;
  const int o0 = blockIdx.y * 64;
  const int b  = blockIdx.z;
  const int t  = threadIdx.x;
  const int w = t >> 6, lane = t & 63, qd = lane >> 4, l = lane & 15;

  __shared__ unsigned short Wl[64 * 64];
  __shared__ unsigned short Xl[64 * 64];

  floatx4 acc[4];
  #pragma unroll
  for (int ns = 0; ns < 4; ++ns) acc[ns] = (floatx4){0.f, 0.f, 0.f, 0.f};

  for (int k0 = 0; k0 < Ci; k0 += 64) {
    const unsigned short* Xs; int cb, rl;
    if (variant == 1) { Xs = (o0 < 256) ? X0 : X1; cb = k0; rl = Ci; }
    else if (k0 < Ci0) { Xs = X0; cb = k0; rl = Ci0; }
    else               { Xs = X1; cb = k0 - Ci0; rl = Ci - Ci0; }
    __syncthreads();
    #pragma unroll
    for (int i = 0; i < 2; ++i) {
      const int idx = i * 256 + t;
      const int row = idx >> 3, pg = idx & 7, sg = pg ^ (row & 7);
      gload16(&Wb[(size_t)(o0 + row) * Ci + k0 + sg * 8], &Wl[row * 64 + pg * 8]);
      gload16(&Xs[((size_t)b * N + n0 + row) * rl + cb + sg * 8], &Xl[row * 64 + pg * 8]);
    }
    __syncthreads();

    const int ar = 16 * w + l;
    const short8 a0 = *(const short8*)&Wl[ar * 64 + ((qd ^ (ar & 7))) * 8];
    const short8 a1 = *(const short8*)&Wl[ar * 64 + (((4 + qd) ^ (ar & 7))) * 8];
    #pragma unroll
    for (int ns = 0; ns < 4; ++ns) {
      const int br = 16 * ns + l;
      const short8 b0 = *(const short8*)&Xl[br * 64 + ((qd ^ (br & 7))) * 8];
      const short8 b1 = *(const short8*)&Xl[br * 64 + (((4 + qd) ^ (br & 7))) * 8];
      acc[ns] = __builtin_amdgcn_mfma_f32_16x16x32_bf16(a0, b0, acc[ns], 0, 0, 0);
      acc[ns] = __builtin_amdgcn_mfma_f32_16x16x32_bf16(a1, b1, acc[ns], 0, 0, 0);
    }
  }

  const int o4 = o0 + 16 * w + qd * 4;   // + rg
  const float4 bi = *(const float4*)&bias[o4];

  if (variant == 4) {
    unsigned short* C = (unsigned short*)O0;
    float s1[4] = {}, s2[4] = {};
    #pragma unroll
    for (int ns = 0; ns < 4; ++ns) {
      const int n = n0 + 16 * ns + l;
      float v[4];
      v[0] = acc[ns][0] + bi.x; v[1] = acc[ns][1] + bi.y;
      v[2] = acc[ns][2] + bi.z; v[3] = acc[ns][3] + bi.w;
      ushort4 pk;
      pk.x = f2bf(v[0]); pk.y = f2bf(v[1]); pk.z = f2bf(v[2]); pk.w = f2bf(v[3]);
      *(ushort4*)&C[((size_t)b * N + n) * Co + o4] = pk;
      #pragma unroll
      for (int rg = 0; rg < 4; ++rg) {
        s1[rg] += v[rg];
        s2[rg] += v[rg] * v[rg];
      }
    }
    #pragma unroll
    for (int rg = 0; rg < 4; ++rg) {
      float a = s1[rg], c2 = s2[rg];
      a  += __shfl_xor(a, 1);  c2 += __shfl_xor(c2, 1);
      a  += __shfl_xor(a, 2);  c2 += __shfl_xor(c2, 2);
      a  += __shfl_xor(a, 4);  c2 += __shfl_xor(c2, 4);
      a  += __shfl_xor(a, 8);  c2 += __shfl_xor(c2, 8);
      if (l == 0) {
        atomicAdd(&Ps [b * 512 + o4 + rg], a);
        atomicAdd(&Ps2[b * 512 + o4 + rg], c2);
      }
    }
    return;
  }

  #pragma unroll
  for (int ns = 0; ns < 4; ++ns) {
    const int n = n0 + 16 * ns + l;
    if (variant == 0) {
      unsigned short* C = (unsigned short*)O0;
      ushort4 pk;
      pk.x = f2bf(acc[ns][0] + bi.x); pk.y = f2bf(acc[ns][1] + bi.y);
      pk.z = f2bf(acc[ns][2] + bi.z); pk.w = f2bf(acc[ns][3] + bi.w);
      *(ushort4*)&C[((size_t)b * N + n) * Co + o4] = pk;
    } else if (variant == 1) {
      if (o0 < 256) {
        unsigned short* C = (unsigned short*)O0;
        ushort4 pk;
        pk.x = f2bf(acc[ns][0] + bi.x); pk.y = f2bf(acc[ns][1] + bi.y);
        pk.z = f2bf(acc[ns][2] + bi.z); pk.w = f2bf(acc[ns][3] + bi.w);
        *(ushort4*)&C[((size_t)b * N + n) * 256 + o4] = pk;
      } else if (o0 < 512) {
        unsigned short* C = (unsigned short*)O1;
        ushort4 pk;
        pk.x = f2bf(acc[ns][0] + bi.x); pk.y = f2bf(acc[ns][1] + bi.y);
        pk.z = f2bf(acc[ns][2] + bi.z); pk.w = f2bf(acc[ns][3] + bi.w);
        *(ushort4*)&C[((size_t)b * N + n) * 256 + (o4 - 256)] = pk;
      } else {
        unsigned short* C = (unsigned short*)O2;
        #pragma unroll
        for (int rg = 0; rg < 4; ++rg) {
          const int op = o4 - 512 + rg, h = op >> 6, d = op & 63;
          C[(((size_t)b * 4 + h) * 64 + d) * N + n] =
              f2bf(acc[ns][rg] + ((const float*)&bi)[rg]);
        }
      }
    } else {
      float* C = (float*)O0;
      #pragma unroll
      for (int rg = 0; rg < 4; ++rg)
        C[((size_t)b * Co + o4 + rg) * N + n] = acc[ns][rg] + ((const float*)&bi)[rg];
    }
  }
}

// ---------------------------------------------------------------------------
// MFMA flash attention (r7 proven, 85us): split-K x4, 128 q/block, 64-key
// tiles, 24KB LDS. Fixed-shift exp2 softmax; partials additive.
// Grid (N/128, H, B*4).
// ---------------------------------------------------------------------------
__global__ __launch_bounds__(256) void attn_mfma(
    const unsigned short* __restrict__ qb, const unsigned short* __restrict__ kb,
    const unsigned short* __restrict__ vh, unsigned short* __restrict__ Opart,
    float* __restrict__ liPart, int N)
{
  const int qt = blockIdx.x;
  const int h  = blockIdx.y;
  const int b  = blockIdx.z >> 2, s = blockIdx.z & 3;
  const int n0 = qt * 128;
  const int t  = threadIdx.x;
  const int w = t >> 6, lane = t & 63, qd = lane >> 4, l = lane & 15;

  __shared__ unsigned short Kl[64 * 64];     // [key][d] swizzled
  __shared__ unsigned short Vl[64 * 64];     // [d][key] swizzled
  __shared__ unsigned short Pl[4][16 * 64];  // wave-private [q][key] swizzled

  const unsigned short* qp0 = &qb[((size_t)b * N + n0 + 16 * w + l) * 256 + h * 64];
  const unsigned short* qp1 = qp0 + (size_t)64 * 256;
  short8 aQ[2][2];
  aQ[0][0] = *(const short8*)&qp0[qd * 8];
  aQ[0][1] = *(const short8*)&qp0[32 + qd * 8];
  aQ[1][0] = *(const short8*)&qp1[qd * 8];
  aQ[1][1] = *(const short8*)&qp1[32 + qd * 8];

  floatx4 accO[2][4];
  #pragma unroll
  for (int qs = 0; qs < 2; ++qs)
    #pragma unroll
    for (int ds = 0; ds < 4; ++ds) accO[qs][ds] = (floatx4){0.f, 0.f, 0.f, 0.f};
  float li[2][4] = {};

  const int j0base = s * 1024;
  for (int jt = 0; jt < 16; ++jt) {
    const int j0 = j0base + jt * 64;
    __syncthreads();
    #pragma unroll
    for (int i = 0; i < 2; ++i) {
      const int idx = i * 256 + t;
      const int row = idx >> 3, pg = idx & 7, sg = pg ^ (row & 7);
      gload16(&kb[((size_t)b * N + j0 + row) * 256 + h * 64 + sg * 8],
              &Kl[row * 64 + pg * 8]);
      gload16(&vh[(((size_t)b * 4 + h) * 64 + row) * N + j0 + sg * 8],
              &Vl[row * 64 + pg * 8]);
    }
    __syncthreads();

    // hoist K/V frags (shared across both q-sets)
    short8 kf[4][2], vf[4][2];
    #pragma unroll
    for (int js = 0; js < 4; ++js) {
      const int br = 16 * js + l;
      kf[js][0] = *(const short8*)&Kl[br * 64 + ((qd ^ (br & 7))) * 8];
      kf[js][1] = *(const short8*)&Kl[br * 64 + (((4 + qd) ^ (br & 7))) * 8];
      vf[js][0] = *(const short8*)&Vl[br * 64 + ((qd ^ (br & 7))) * 8];
      vf[js][1] = *(const short8*)&Vl[br * 64 + (((4 + qd) ^ (br & 7))) * 8];
    }

    #pragma unroll
    for (int qs = 0; qs < 2; ++qs) {
      floatx4 S[4];
      #pragma unroll
      for (int js = 0; js < 4; ++js) {
        floatx4 a = (floatx4){0.f, 0.f, 0.f, 0.f};
        a = __builtin_amdgcn_mfma_f32_16x16x32_bf16(aQ[qs][0], kf[js][0], a, 0, 0, 0);
        a = __builtin_amdgcn_mfma_f32_16x16x32_bf16(aQ[qs][1], kf[js][1], a, 0, 0, 0);
        S[js] = a;
      }
      #pragma unroll
      for (int js = 0; js < 4; ++js) {
        const int kg = 2 * js + (l >> 3);
        #pragma unroll
        for (int rg = 0; rg < 4; ++rg) {
          const float pv = __builtin_exp2f(S[js][rg]);
          li[qs][rg] += pv;
          union { float f; unsigned int u; } cv; cv.f = pv;
          const int qr = qd * 4 + rg;
          Pl[w][qr * 64 + ((kg ^ (qr & 7))) * 8 + (l & 7)] =
              (unsigned short)((cv.u + 0x8000u) >> 16);
        }
      }
      const short8 aP0 = *(const short8*)&Pl[w][l * 64 + ((qd ^ (l & 7))) * 8];
      const short8 aP1 = *(const short8*)&Pl[w][l * 64 + (((4 + qd) ^ (l & 7))) * 8];
      #pragma unroll
      for (int ds = 0; ds < 4; ++ds) {
        accO[qs][ds] = __builtin_amdgcn_mfma_f32_16x16x32_bf16(aP0, vf[ds][0], accO[qs][ds], 0, 0, 0);
        accO[qs][ds] = __builtin_amdgcn_mfma_f32_16x16x32_bf16(aP1, vf[ds][1], accO[qs][ds], 0, 0, 0);
      }
    }
  }

  const size_t obase = ((((size_t)b * 4 + h) * 4 + s) * 32 + qt) * 128;
  #pragma unroll
  for (int qs = 0; qs < 2; ++qs)
    #pragma unroll
    for (int rg = 0; rg < 4; ++rg) {
      float sum = li[qs][rg];
      sum += __shfl_xor(sum, 1);
      sum += __shfl_xor(sum, 2);
      sum += __shfl_xor(sum, 4);
      sum += __shfl_xor(sum, 8);
      const int q = qs * 64 + 16 * w + qd * 4 + rg;
      #pragma unroll
      for (int ds = 0; ds < 4; ++ds)
        Opart[(obase + q) * 64 + 16 * ds + l] = f2bf(accO[qs][ds][rg]);
      if (l == 0) liPart[obase + q] = sum;
    }
}

// ---------------------------------------------------------------------------
// Combine 4 split-K partials -> atb NHC head-major bf16. Grid (N/128, H, B).
// ---------------------------------------------------------------------------
__global__ __launch_bounds__(256) void attn_combine(
    const unsigned short* __restrict__ Opart, const float* __restrict__ liPart,
    unsigned short* __restrict__ atb, int N)
{
  const int qt = blockIdx.x, h = blockIdx.y, b = blockIdx.z;
  const int t = threadIdx.x;
  const int q = t >> 1, d0 = (t & 1) * 32;

  float li = 0.f;
  size_t idx[4];
  #pragma unroll
  for (int s = 0; s < 4; ++s) {
    idx[s] = ((((size_t)b * 4 + h) * 4 + s) * 32 + qt) * 128 + q;
    li += liPart[idx[s]];
  }
  const float inv = 1.f / li;

  float o[32];
  #pragma unroll
  for (int c = 0; c < 32; ++c) o[c] = 0.f;
  #pragma unroll
  for (int s = 0; s < 4; ++s) {
    #pragma unroll
    for (int c4 = 0; c4 < 4; ++c4) {
      const short8 v = *(const short8*)&Opart[idx[s] * 64 + d0 + c4 * 8];
      #pragma unroll
      for (int j = 0; j < 8; ++j) o[c4 * 8 + j] += bf2f((unsigned short)v[j]);
    }
  }
  unsigned short* dst = &atb[((size_t)b * N + qt * 128 + q) * 256 + h * 64 + d0];
  #pragma unroll
  for (int c4 = 0; c4 < 4; ++c4) {
    ushort4 pk;
    pk.x = f2bf(o[c4 * 8 + 0] * inv); pk.y = f2bf(o[c4 * 8 + 1] * inv);
    pk.z = f2bf(o[c4 * 8 + 2] * inv); pk.w = f2bf(o[c4 * 8 + 3] * inv);
    *(ushort4*)&dst[c4 * 8] = pk;
    pk.x = f2bf(o[c4 * 8 + 4] * inv); pk.y = f2bf(o[c4 * 8 + 5] * inv);
    pk.z = f2bf(o[c4 * 8 + 6] * inv); pk.w = f2bf(o[c4 * 8 + 7] * inv);
    *(ushort4*)&dst[c4 * 8 + 4] = pk;
  }
}

// ---------------------------------------------------------------------------
// InstanceNorm finalize+normalize from fused stats. Grid (8, 16, B).
// ---------------------------------------------------------------------------
__global__ __launch_bounds__(256) void in_norm(
    unsigned short* __restrict__ H, const float* __restrict__ Ps,
    const float* __restrict__ Ps2, int N)
{
  const int cg = blockIdx.x, ns = blockIdx.y, b = blockIdx.z, t = threadIdx.x;
  __shared__ float muS[64], ivS[64];
  if (t < 64) {
    const int c = cg * 64 + t;
    const float mu = Ps[b * 512 + c] / (float)N;
    const float var = fmaxf(Ps2[b * 512 + c] / (float)N - mu * mu, 0.f);
    muS[t] = mu;
    ivS[t] = rsqrtf(var + 1e-5f);
  }
  __syncthreads();
  const int c0 = cg * 64 + (t & 7) * 8;
  float mu[8], iv[8];
  #pragma unroll
  for (int j = 0; j < 8; ++j) {
    mu[j] = muS[(t & 7) * 8 + j];
    iv[j] = ivS[(t & 7) * 8 + j];
  }
  #pragma unroll
  for (int i = 0; i < 8; ++i) {
    const int n = ns * 256 + (t >> 3) + i * 32;
    unsigned short* p = &H[((size_t)b * N + n) * 512 + c0];
    short8 hv = *(const short8*)p;
    #pragma unroll
    for (int j = 0; j < 8; ++j) {
      const float f = fmaxf((bf2f((unsigned short)hv[j]) - mu[j]) * iv[j], 0.f);
      hv[j] = (short)f2bf(f);
    }
    *(short8*)p = hv;
  }
}

// ---------------------------------------------------------------------------
extern "C" void kernel_launch(void* const* d_in, const int* in_sizes, int n_in,
                              void* d_out, int out_size, void* d_ws, size_t ws_size,
                              hipStream_t stream)
{
  const int B = 2, D = 256, N = 4096;

  const float* x   = (const float*)d_in[0];
  const float* src = (const float*)d_in[1];
  const float* Wq  = (const float*)d_in[2];  const float* bq = (const float*)d_in[3];
  const float* Wk  = (const float*)d_in[4];  const float* bk = (const float*)d_in[5];
  const float* Wv  = (const float*)d_in[6];  const float* bv = (const float*)d_in[7];
  const float* Wm  = (const float*)d_in[8];  const float* bm = (const float*)d_in[9];
  const float* W1  = (const float*)d_in[10]; const float* b1 = (const float*)d_in[11];
  const float* W2  = (const float*)d_in[12]; const float* b2 = (const float*)d_in[13];
  float* out = (float*)d_out;

  char* ws = (char*)d_ws;
  const size_t MB = 1u << 20;
  unsigned short* xb  = (unsigned short*)(ws + 0 * MB);
  unsigned short* sb  = (unsigned short*)(ws + 4 * MB);
  unsigned short* qbf = (unsigned short*)(ws + 8 * MB);
  unsigned short* kbf = (unsigned short*)(ws + 12 * MB);
  unsigned short* vhb = (unsigned short*)(ws + 16 * MB);
  unsigned short* atb = (unsigned short*)(ws + 20 * MB);
  unsigned short* Opart = (unsigned short*)(ws + 24 * MB);  // dead after combine
  unsigned short* msb = (unsigned short*)(ws + 24 * MB);    // NHC 256 (post-combine)
  unsigned short* hb  = (unsigned short*)(ws + 28 * MB);    // [b][n][512]
  float* liPart = (float*)(ws + 41 * MB);
  unsigned short* wqkvb = (unsigned short*)(ws + 42 * MB);  // [768][256]
  unsigned short* wmb = wqkvb + 768 * 256;                  // [256][256]
  unsigned short* w1b = wmb + 256 * 256;                    // [512][512]
  unsigned short* w2b = w1b + 512 * 512;                    // [256][512]
  float* biasb = (float*)(ws + 44 * MB);                    // 1792 used
  float* Ps    = biasb + 2048;                              // 1024
  float* Ps2   = Ps + 1024;                                 // 1024

  const dim3 blk(256);

  tx_all<<<dim3(N / 32, D / 32, 2 * B), blk, 0, stream>>>(x, src, xb, sb, D, N);
  wprep<<<dim3(2568), blk, 0, stream>>>(Wq, Wk, Wv, Wm, W1, W2,
                                        bq, bk, bv, bm, b1, b2,
                                        wqkvb, wmb, w1b, w2b, biasb, Ps);

  // fused q/k/v (Co=768, 64-o sections: 0-3 q from xb, 4-7 k, 8-11 v from sb)
  gemm64<<<dim3(N / 64, 12, B), blk, 0, stream>>>(
      wqkvb, biasb, xb, sb, qbf, kbf, vhb, 768, 256, 256, N, 1, nullptr, nullptr);

  attn_mfma<<<dim3(N / 128, 4, B * 4), blk, 0, stream>>>(
      qbf, kbf, vhb, Opart, liPart, N);
  attn_combine<<<dim3(N / 128, 4, B), blk, 0, stream>>>(Opart, liPart, atb, N);

  // message (cols head-major-permuted to match atb)
  gemm64<<<dim3(N / 64, 4, B), blk, 0, stream>>>(
      wmb, biasb + 768, atb, atb, msb, nullptr, nullptr, 256, 256, 256, N, 0,
      nullptr, nullptr);

  // h = W1 @ [x; msg] + b1, with fused InstanceNorm stats (variant 4)
  gemm64<<<dim3(N / 64, 8, B), blk, 0, stream>>>(
      w1b, biasb + 1024, xb, msb, hb, nullptr, nullptr,
      512, 512, 256, N, 4, Ps, Ps2);

  in_norm<<<dim3(8, 16, B), blk, 0, stream>>>(hb, Ps, Ps2, N);

  // out = W2 @ h (fp32 CHN)
  gemm64<<<dim3(N / 64, 4, B), blk, 0, stream>>>(
      w2b, biasb + 1536, hb, hb, out, nullptr, nullptr,
      256, 512, 512, N, 2, nullptr, nullptr);
}

// Round 12
// 234.292 us; speedup vs baseline: 1.1143x; 1.0176x over previous
//
#include <hip/hip_runtime.h>
#include <cstdint>
#include <cstddef>

// fp32 I/O (verified r3). Internals: bf16 NHC activations + MFMA everywhere.
// mfma_f32_16x16x32_bf16 layouts (HW-verified m89/m120):
//   A: m=lane&15, k=quad*8+j   B: n=lane&15, k=quad*8+j
//   C/D: col(n)=lane&15, row(m)=quad*4+reg
// LDS tiles [row][64] bf16; XOR swizzle applied at the GLOBAL source chunk
// (sg = pg ^ (row&7)) so global_load_lds lands the swizzled image directly.
// *** global_load_lds RULE (m104/m108): LDS dest = wave-uniform base +
// lane*16 — every staging dest offset MUST be linear in lane (= idx*16B). ***
// Softmax: fixed-shift exp2 (exact by shift-invariance; |S| << 88 overflow),
// log2(e)/8 folded into Wq/bq. Split-K partials additive (no max state).
// r12: GEMMs back to 128x128 (r10-proven; 64-tile halves arithmetic
// intensity -> 2x staging traffic, regressed rest 139->153). in_norm fused
// into W2's X-staging (variant 5, VALU path, bit-identical math). tx_all +
// wprep merged into one prep dispatch. 9 -> 7 dispatches.

typedef __attribute__((ext_vector_type(8))) short short8;
typedef __attribute__((ext_vector_type(4))) float floatx4;

__device__ __forceinline__ unsigned short f2bf(float x) {
  union { float f; unsigned int u; } c; c.f = x;
  unsigned int r = c.u + 0x7FFFu + ((c.u >> 16) & 1u);   // RNE
  return (unsigned short)(r >> 16);
}
__device__ __forceinline__ float bf2f(unsigned short u) {
  union { unsigned int i; float f; } c; c.i = ((unsigned int)u) << 16; return c.f;
}
__device__ __forceinline__ void gload16(const void* g, void* l) {
  __builtin_amdgcn_global_load_lds(
      (const __attribute__((address_space(1))) unsigned int*)g,
      (__attribute__((address_space(3))) unsigned int*)l, 16, 0, 0);
}

#define LOG2E_8 0.18033688011112042f

// ---------------------------------------------------------------------------
// prep: input transpose+convert AND all weight/bias prep in ONE dispatch.
// bid < 4096: tx (x/src [b][c][n] fp32 -> NHC bf16), grid-flattened (128,8,4).
// bid >= 4096: weight converts (wbid = bid-4096, 0..2567).
// ---------------------------------------------------------------------------
__global__ __launch_bounds__(256) void prep(
    const float* __restrict__ x, const float* __restrict__ src,
    unsigned short* __restrict__ xb, unsigned short* __restrict__ sb,
    const float* __restrict__ Wq, const float* __restrict__ Wk,
    const float* __restrict__ Wv, const float* __restrict__ Wm,
    const float* __restrict__ W1, const float* __restrict__ W2,
    const float* __restrict__ bq, const float* __restrict__ bk,
    const float* __restrict__ bv, const float* __restrict__ bm,
    const float* __restrict__ b1, const float* __restrict__ b2,
    unsigned short* __restrict__ wqkv, unsigned short* __restrict__ wmb,
    unsigned short* __restrict__ w1b, unsigned short* __restrict__ w2b,
    float* __restrict__ biasb, float* __restrict__ Pzero, int C, int N)
{
  __shared__ float tile[32][33];
  const int bid = blockIdx.x, t = threadIdx.x;

  if (bid < 4096) {
    const int xg = bid & 127, yg = (bid >> 7) & 7, zg = bid >> 10;
    const int which = zg >> 1, b = zg & 1;
    const float* X = which ? src : x;
    unsigned short* Y = which ? sb : xb;
    const int n0 = xg * 32, c0 = yg * 32;
    const int tc = t & 31, tr = t >> 5;
    #pragma unroll
    for (int i = 0; i < 4; ++i)
      tile[tr + i * 8][tc] = X[((size_t)b * C + c0 + tr + i * 8) * N + n0 + tc];
    __syncthreads();
    #pragma unroll
    for (int i = 0; i < 4; ++i)
      Y[((size_t)b * N + n0 + tr + i * 8) * C + c0 + tc] = f2bf(tile[tc][tr + i * 8]);
    return;
  }

  const int wbid = bid - 4096;
  if (wbid < 768) {
    const int idx = wbid * 256 + t;
    const int op = idx >> 8, ip = idx & 255;
    const int grp = op >> 8, oo = op & 255;
    const int o = 4 * (oo & 63) + (oo >> 6);
    const float* W = grp == 0 ? Wq : grp == 1 ? Wk : Wv;
    const float sc = grp == 0 ? LOG2E_8 : 1.f;
    wqkv[idx] = f2bf(W[(size_t)o * 256 + ip] * sc);
  } else if (wbid < 1024) {
    const int idx = (wbid - 768) * 256 + t;
    const int o = idx >> 8, ip = idx & 255;
    const int i2 = 4 * (ip & 63) + (ip >> 6);
    wmb[idx] = f2bf(Wm[(size_t)o * 256 + i2]);
  } else if (wbid < 2048) {
    const int idx = (wbid - 1024) * 256 + t;
    w1b[idx] = f2bf(W1[idx]);
  } else if (wbid < 2560) {
    const int idx = (wbid - 2048) * 256 + t;
    w2b[idx] = f2bf(W2[idx]);
  } else if (wbid < 2567) {
    const int z = (wbid - 2560) * 256 + t;
    if (z < 256)       biasb[z] = bq[4 * (z & 63) + (z >> 6)] * LOG2E_8;
    else if (z < 512)  { const int y = z - 256; biasb[z] = bk[4 * (y & 63) + (y >> 6)]; }
    else if (z < 768)  { const int y = z - 512; biasb[z] = bv[4 * (y & 63) + (y >> 6)]; }
    else if (z < 1024) biasb[z] = bm[z - 768];
    else if (z < 1536) biasb[z] = b1[z - 1024];
    else if (z < 1792) biasb[z] = b2[z - 1536];
  } else {
    #pragma unroll
    for (int k = 0; k < 8; ++k) Pzero[k * 256 + t] = 0.f;
  }
}

// ---------------------------------------------------------------------------
// 128x128-tile MFMA GEMM, global_load_lds staging (dest = idx*16B linear).
// C[b,o,n] = sum_i W[o,i]*X[b,n,i] + bias[o]. Grid (N/128, Co/128, B).
// variant 0: NHC bf16 out O0
// variant 1: fused qkv (q->O0, k->O1 NHC 256; v->O2 [b][h][d][n])
// variant 2: CHN fp32 out O0
// variant 4: NHC bf16 out O0 + fp32 stats atomics into Ps/Ps2 (per channel o)
// variant 5: X staged via VALU with fused InstanceNorm(Ps,Ps2)+ReLU
//            (bit-identical to the old in_norm kernel); fp32 CHN out.
// ---------------------------------------------------------------------------
__global__ __launch_bounds__(256) void gemm128(
    const unsigned short* __restrict__ Wb, const float* __restrict__ bias,
    const unsigned short* __restrict__ X0, const unsigned short* __restrict__ X1,
    void* __restrict__ O0, void* __restrict__ O1, void* __restrict__ O2,
    int Co, int Ci, int Ci0, int N, int variant,
    float* __restrict__ Ps, float* __restrict__ Ps2)
{
  const int n0 = blockIdx.x * 128;
  const int o0 = blockIdx.y * 128;
  const int b  = blockIdx.z;
  const int t  = threadIdx.x;
  const int w = t >> 6, lane = t & 63, qd = lane >> 4, l = lane & 15;
  const int oh = (w >> 1) * 64, nh = (w & 1) * 64;

  __shared__ unsigned short Wl[128 * 64];
  __shared__ unsigned short Xl[128 * 64];
  __shared__ float nstat[1024];   // variant 5: mu[512] | inv[512]

  if (variant == 5) {
    for (int c = t; c < 512; c += 256) {
      const float mu = Ps[b * 512 + c] / (float)N;
      const float var = fmaxf(Ps2[b * 512 + c] / (float)N - mu * mu, 0.f);
      nstat[c] = mu;
      nstat[512 + c] = rsqrtf(var + 1e-5f);
    }
  }

  floatx4 acc[4][4];
  #pragma unroll
  for (int i = 0; i < 4; ++i)
    #pragma unroll
    for (int j = 0; j < 4; ++j) acc[i][j] = (floatx4){0.f, 0.f, 0.f, 0.f};

  for (int k0 = 0; k0 < Ci; k0 += 64) {
    const unsigned short* Xs; int cb, rl;
    if (variant == 1) { Xs = (o0 < 256) ? X0 : X1; cb = k0; rl = Ci; }
    else if (k0 < Ci0) { Xs = X0; cb = k0; rl = Ci0; }
    else               { Xs = X1; cb = k0 - Ci0; rl = Ci - Ci0; }
    __syncthreads();
    if (variant == 5) {
      #pragma unroll
      for (int i = 0; i < 4; ++i) {
        const int idx = i * 256 + t;
        const int row = idx >> 3, pg = idx & 7, sg = pg ^ (row & 7);
        gload16(&Wb[(size_t)(o0 + row) * Ci + k0 + sg * 8], &Wl[row * 64 + pg * 8]);
        const int c = k0 + sg * 8;
        const short8 hv = *(const short8*)&X0[((size_t)b * N + n0 + row) * 512 + c];
        short8 ov;
        #pragma unroll
        for (int j = 0; j < 8; ++j) {
          const float f = fmaxf((bf2f((unsigned short)hv[j]) - nstat[c + j]) *
                                    nstat[512 + c + j], 0.f);
          ov[j] = (short)f2bf(f);
        }
        *(short8*)&Xl[row * 64 + pg * 8] = ov;
      }
    } else {
      #pragma unroll
      for (int i = 0; i < 4; ++i) {
        const int idx = i * 256 + t;
        const int row = idx >> 3, pg = idx & 7, sg = pg ^ (row & 7);
        gload16(&Wb[(size_t)(o0 + row) * Ci + k0 + sg * 8], &Wl[row * 64 + pg * 8]);
        gload16(&Xs[((size_t)b * N + n0 + row) * rl + cb + sg * 8], &Xl[row * 64 + pg * 8]);
      }
    }
    __syncthreads();

    short8 af[4][2], bf[4][2];
    #pragma unroll
    for (int i = 0; i < 4; ++i) {
      const int ar = oh + 16 * i + l;
      af[i][0] = *(const short8*)&Wl[ar * 64 + ((qd ^ (ar & 7))) * 8];
      af[i][1] = *(const short8*)&Wl[ar * 64 + (((4 + qd) ^ (ar & 7))) * 8];
    }
    #pragma unroll
    for (int j = 0; j < 4; ++j) {
      const int br = nh + 16 * j + l;
      bf[j][0] = *(const short8*)&Xl[br * 64 + ((qd ^ (br & 7))) * 8];
      bf[j][1] = *(const short8*)&Xl[br * 64 + (((4 + qd) ^ (br & 7))) * 8];
    }
    #pragma unroll
    for (int i = 0; i < 4; ++i)
      #pragma unroll
      for (int j = 0; j < 4; ++j) {
        acc[i][j] = __builtin_amdgcn_mfma_f32_16x16x32_bf16(af[i][0], bf[j][0], acc[i][j], 0, 0, 0);
        acc[i][j] = __builtin_amdgcn_mfma_f32_16x16x32_bf16(af[i][1], bf[j][1], acc[i][j], 0, 0, 0);
      }
  }

  const int osec = o0 + oh;
  if (variant == 4) {
    unsigned short* C = (unsigned short*)O0;
    float s1[4][4], s2[4][4];
    #pragma unroll
    for (int i = 0; i < 4; ++i) {
      const int o4 = o0 + oh + 16 * i + qd * 4;
      const float4 bi = *(const float4*)&bias[o4];
      #pragma unroll
      for (int rg = 0; rg < 4; ++rg) { s1[i][rg] = 0.f; s2[i][rg] = 0.f; }
      #pragma unroll
      for (int j = 0; j < 4; ++j) {
        const int n = n0 + nh + 16 * j + l;
        float v[4];
        v[0] = acc[i][j][0] + bi.x; v[1] = acc[i][j][1] + bi.y;
        v[2] = acc[i][j][2] + bi.z; v[3] = acc[i][j][3] + bi.w;
        ushort4 pk;
        pk.x = f2bf(v[0]); pk.y = f2bf(v[1]); pk.z = f2bf(v[2]); pk.w = f2bf(v[3]);
        *(ushort4*)&C[((size_t)b * N + n) * Co + o4] = pk;
        #pragma unroll
        for (int rg = 0; rg < 4; ++rg) {
          s1[i][rg] += v[rg];
          s2[i][rg] += v[rg] * v[rg];
        }
      }
    }
    #pragma unroll
    for (int i = 0; i < 4; ++i)
      #pragma unroll
      for (int rg = 0; rg < 4; ++rg) {
        float a = s1[i][rg], c2 = s2[i][rg];
        a  += __shfl_xor(a, 1);  c2 += __shfl_xor(c2, 1);
        a  += __shfl_xor(a, 2);  c2 += __shfl_xor(c2, 2);
        a  += __shfl_xor(a, 4);  c2 += __shfl_xor(c2, 4);
        a  += __shfl_xor(a, 8);  c2 += __shfl_xor(c2, 8);
        if (l == 0) {
          const int o = o0 + oh + 16 * i + qd * 4 + rg;
          atomicAdd(&Ps [b * 512 + o], a);
          atomicAdd(&Ps2[b * 512 + o], c2);
        }
      }
    return;
  }

  #pragma unroll
  for (int i = 0; i < 4; ++i) {
    const int o4 = o0 + oh + 16 * i + qd * 4;
    const float4 bi = *(const float4*)&bias[o4];
    #pragma unroll
    for (int j = 0; j < 4; ++j) {
      const int n = n0 + nh + 16 * j + l;
      if (variant == 0) {
        unsigned short* C = (unsigned short*)O0;
        ushort4 pk;
        pk.x = f2bf(acc[i][j][0] + bi.x); pk.y = f2bf(acc[i][j][1] + bi.y);
        pk.z = f2bf(acc[i][j][2] + bi.z); pk.w = f2bf(acc[i][j][3] + bi.w);
        *(ushort4*)&C[((size_t)b * N + n) * Co + o4] = pk;
      } else if (variant == 1) {
        if (osec < 256) {
          unsigned short* C = (unsigned short*)O0;
          ushort4 pk;
          pk.x = f2bf(acc[i][j][0] + bi.x); pk.y = f2bf(acc[i][j][1] + bi.y);
          pk.z = f2bf(acc[i][j][2] + bi.z); pk.w = f2bf(acc[i][j][3] + bi.w);
          *(ushort4*)&C[((size_t)b * N + n) * 256 + o4] = pk;
        } else if (osec < 512) {
          unsigned short* C = (unsigned short*)O1;
          ushort4 pk;
          pk.x = f2bf(acc[i][j][0] + bi.x); pk.y = f2bf(acc[i][j][1] + bi.y);
          pk.z = f2bf(acc[i][j][2] + bi.z); pk.w = f2bf(acc[i][j][3] + bi.w);
          *(ushort4*)&C[((size_t)b * N + n) * 256 + (o4 - 256)] = pk;
        } else {
          unsigned short* C = (unsigned short*)O2;
          #pragma unroll
          for (int rg = 0; rg < 4; ++rg) {
            const int op = o4 - 512 + rg, h = op >> 6, d = op & 63;
            C[(((size_t)b * 4 + h) * 64 + d) * N + n] =
                f2bf(acc[i][j][rg] + ((const float*)&bi)[rg]);
          }
        }
      } else {  // variant 2 or 5: CHN fp32
        float* C = (float*)O0;
        #pragma unroll
        for (int rg = 0; rg < 4; ++rg)
          C[((size_t)b * Co + o4 + rg) * N + n] = acc[i][j][rg] + ((const float*)&bi)[rg];
      }
    }
  }
}

// ---------------------------------------------------------------------------
// MFMA flash attention (r7/r11 proven, 85us): split-K x4, 128 q/block,
// 64-key tiles, 24KB LDS. Grid (N/128, H, B*4).
// ---------------------------------------------------------------------------
__global__ __launch_bounds__(256) void attn_mfma(
    const unsigned short* __restrict__ qb, const unsigned short* __restrict__ kb,
    const unsigned short* __restrict__ vh, unsigned short* __restrict__ Opart,
    float* __restrict__ liPart, int N)
{
  const int qt = blockIdx.x;
  const int h  = blockIdx.y;
  const int b  = blockIdx.z >> 2, s = blockIdx.z & 3;
  const int n0 = qt * 128;
  const int t  = threadIdx.x;
  const int w = t >> 6, lane = t & 63, qd = lane >> 4, l = lane & 15;

  __shared__ unsigned short Kl[64 * 64];     // [key][d] swizzled
  __shared__ unsigned short Vl[64 * 64];     // [d][key] swizzled
  __shared__ unsigned short Pl[4][16 * 64];  // wave-private [q][key] swizzled

  const unsigned short* qp0 = &qb[((size_t)b * N + n0 + 16 * w + l) * 256 + h * 64];
  const unsigned short* qp1 = qp0 + (size_t)64 * 256;
  short8 aQ[2][2];
  aQ[0][0] = *(const short8*)&qp0[qd * 8];
  aQ[0][1] = *(const short8*)&qp0[32 + qd * 8];
  aQ[1][0] = *(const short8*)&qp1[qd * 8];
  aQ[1][1] = *(const short8*)&qp1[32 + qd * 8];

  floatx4 accO[2][4];
  #pragma unroll
  for (int qs = 0; qs < 2; ++qs)
    #pragma unroll
    for (int ds = 0; ds < 4; ++ds) accO[qs][ds] = (floatx4){0.f, 0.f, 0.f, 0.f};
  float li[2][4] = {};

  const int j0base = s * 1024;
  for (int jt = 0; jt < 16; ++jt) {
    const int j0 = j0base + jt * 64;
    __syncthreads();
    #pragma unroll
    for (int i = 0; i < 2; ++i) {
      const int idx = i * 256 + t;
      const int row = idx >> 3, pg = idx & 7, sg = pg ^ (row & 7);
      gload16(&kb[((size_t)b * N + j0 + row) * 256 + h * 64 + sg * 8],
              &Kl[row * 64 + pg * 8]);
      gload16(&vh[(((size_t)b * 4 + h) * 64 + row) * N + j0 + sg * 8],
              &Vl[row * 64 + pg * 8]);
    }
    __syncthreads();

    short8 kf[4][2], vf[4][2];
    #pragma unroll
    for (int js = 0; js < 4; ++js) {
      const int br = 16 * js + l;
      kf[js][0] = *(const short8*)&Kl[br * 64 + ((qd ^ (br & 7))) * 8];
      kf[js][1] = *(const short8*)&Kl[br * 64 + (((4 + qd) ^ (br & 7))) * 8];
      vf[js][0] = *(const short8*)&Vl[br * 64 + ((qd ^ (br & 7))) * 8];
      vf[js][1] = *(const short8*)&Vl[br * 64 + (((4 + qd) ^ (br & 7))) * 8];
    }

    #pragma unroll
    for (int qs = 0; qs < 2; ++qs) {
      floatx4 S[4];
      #pragma unroll
      for (int js = 0; js < 4; ++js) {
        floatx4 a = (floatx4){0.f, 0.f, 0.f, 0.f};
        a = __builtin_amdgcn_mfma_f32_16x16x32_bf16(aQ[qs][0], kf[js][0], a, 0, 0, 0);
        a = __builtin_amdgcn_mfma_f32_16x16x32_bf16(aQ[qs][1], kf[js][1], a, 0, 0, 0);
        S[js] = a;
      }
      #pragma unroll
      for (int js = 0; js < 4; ++js) {
        const int kg = 2 * js + (l >> 3);
        #pragma unroll
        for (int rg = 0; rg < 4; ++rg) {
          const float pv = __builtin_exp2f(S[js][rg]);
          li[qs][rg] += pv;
          union { float f; unsigned int u; } cv; cv.f = pv;
          const int qr = qd * 4 + rg;
          Pl[w][qr * 64 + ((kg ^ (qr & 7))) * 8 + (l & 7)] =
              (unsigned short)((cv.u + 0x8000u) >> 16);
        }
      }
      const short8 aP0 = *(const short8*)&Pl[w][l * 64 + ((qd ^ (l & 7))) * 8];
      const short8 aP1 = *(const short8*)&Pl[w][l * 64 + (((4 + qd) ^ (l & 7))) * 8];
      #pragma unroll
      for (int ds = 0; ds < 4; ++ds) {
        accO[qs][ds] = __builtin_amdgcn_mfma_f32_16x16x32_bf16(aP0, vf[ds][0], accO[qs][ds], 0, 0, 0);
        accO[qs][ds] = __builtin_amdgcn_mfma_f32_16x16x32_bf16(aP1, vf[ds][1], accO[qs][ds], 0, 0, 0);
      }
    }
  }

  const size_t obase = ((((size_t)b * 4 + h) * 4 + s) * 32 + qt) * 128;
  #pragma unroll
  for (int qs = 0; qs < 2; ++qs)
    #pragma unroll
    for (int rg = 0; rg < 4; ++rg) {
      float sum = li[qs][rg];
      sum += __shfl_xor(sum, 1);
      sum += __shfl_xor(sum, 2);
      sum += __shfl_xor(sum, 4);
      sum += __shfl_xor(sum, 8);
      const int q = qs * 64 + 16 * w + qd * 4 + rg;
      #pragma unroll
      for (int ds = 0; ds < 4; ++ds)
        Opart[(obase + q) * 64 + 16 * ds + l] = f2bf(accO[qs][ds][rg]);
      if (l == 0) liPart[obase + q] = sum;
    }
}

// ---------------------------------------------------------------------------
// Combine 4 split-K partials -> atb NHC head-major bf16. Grid (N/128, H, B).
// ---------------------------------------------------------------------------
__global__ __launch_bounds__(256) void attn_combine(
    const unsigned short* __restrict__ Opart, const float* __restrict__ liPart,
    unsigned short* __restrict__ atb, int N)
{
  const int qt = blockIdx.x, h = blockIdx.y, b = blockIdx.z;
  const int t = threadIdx.x;
  const int q = t >> 1, d0 = (t & 1) * 32;

  float li = 0.f;
  size_t idx[4];
  #pragma unroll
  for (int s = 0; s < 4; ++s) {
    idx[s] = ((((size_t)b * 4 + h) * 4 + s) * 32 + qt) * 128 + q;
    li += liPart[idx[s]];
  }
  const float inv = 1.f / li;

  float o[32];
  #pragma unroll
  for (int c = 0; c < 32; ++c) o[c] = 0.f;
  #pragma unroll
  for (int s = 0; s < 4; ++s) {
    #pragma unroll
    for (int c4 = 0; c4 < 4; ++c4) {
      const short8 v = *(const short8*)&Opart[idx[s] * 64 + d0 + c4 * 8];
      #pragma unroll
      for (int j = 0; j < 8; ++j) o[c4 * 8 + j] += bf2f((unsigned short)v[j]);
    }
  }
  unsigned short* dst = &atb[((size_t)b * N + qt * 128 + q) * 256 + h * 64 + d0];
  #pragma unroll
  for (int c4 = 0; c4 < 4; ++c4) {
    ushort4 pk;
    pk.x = f2bf(o[c4 * 8 + 0] * inv); pk.y = f2bf(o[c4 * 8 + 1] * inv);
    pk.z = f2bf(o[c4 * 8 + 2] * inv); pk.w = f2bf(o[c4 * 8 + 3] * inv);
    *(ushort4*)&dst[c4 * 8] = pk;
    pk.x = f2bf(o[c4 * 8 + 4] * inv); pk.y = f2bf(o[c4 * 8 + 5] * inv);
    pk.z = f2bf(o[c4 * 8 + 6] * inv); pk.w = f2bf(o[c4 * 8 + 7] * inv);
    *(ushort4*)&dst[c4 * 8 + 4] = pk;
  }
}

// ---------------------------------------------------------------------------
extern "C" void kernel_launch(void* const* d_in, const int* in_sizes, int n_in,
                              void* d_out, int out_size, void* d_ws, size_t ws_size,
                              hipStream_t stream)
{
  const int B = 2, D = 256, N = 4096;

  const float* x   = (const float*)d_in[0];
  const float* src = (const float*)d_in[1];
  const float* Wq  = (const float*)d_in[2];  const float* bq = (const float*)d_in[3];
  const float* Wk  = (const float*)d_in[4];  const float* bk = (const float*)d_in[5];
  const float* Wv  = (const float*)d_in[6];  const float* bv = (const float*)d_in[7];
  const float* Wm  = (const float*)d_in[8];  const float* bm = (const float*)d_in[9];
  const float* W1  = (const float*)d_in[10]; const float* b1 = (const float*)d_in[11];
  const float* W2  = (const float*)d_in[12]; const float* b2 = (const float*)d_in[13];
  float* out = (float*)d_out;

  char* ws = (char*)d_ws;
  const size_t MB = 1u << 20;
  unsigned short* xb  = (unsigned short*)(ws + 0 * MB);
  unsigned short* sb  = (unsigned short*)(ws + 4 * MB);
  unsigned short* qbf = (unsigned short*)(ws + 8 * MB);
  unsigned short* kbf = (unsigned short*)(ws + 12 * MB);
  unsigned short* vhb = (unsigned short*)(ws + 16 * MB);
  unsigned short* atb = (unsigned short*)(ws + 20 * MB);
  unsigned short* Opart = (unsigned short*)(ws + 24 * MB);  // dead after combine
  unsigned short* msb = (unsigned short*)(ws + 24 * MB);    // NHC 256 (post-combine)
  unsigned short* hb  = (unsigned short*)(ws + 28 * MB);    // [b][n][512]
  float* liPart = (float*)(ws + 41 * MB);
  unsigned short* wqkvb = (unsigned short*)(ws + 42 * MB);  // [768][256]
  unsigned short* wmb = wqkvb + 768 * 256;                  // [256][256]
  unsigned short* w1b = wmb + 256 * 256;                    // [512][512]
  unsigned short* w2b = w1b + 512 * 512;                    // [256][512]
  float* biasb = (float*)(ws + 44 * MB);                    // 1792 used
  float* Ps    = biasb + 2048;                              // 1024
  float* Ps2   = Ps + 1024;                                 // 1024

  const dim3 blk(256);

  prep<<<dim3(4096 + 2568), blk, 0, stream>>>(
      x, src, xb, sb, Wq, Wk, Wv, Wm, W1, W2,
      bq, bk, bv, bm, b1, b2, wqkvb, wmb, w1b, w2b, biasb, Ps, D, N);

  // fused q/k/v (Co=768: o<256 q from xb, <512 k, else v from sb)
  gemm128<<<dim3(N / 128, 6, B), blk, 0, stream>>>(
      wqkvb, biasb, xb, sb, qbf, kbf, vhb, 768, 256, 256, N, 1, nullptr, nullptr);

  attn_mfma<<<dim3(N / 128, 4, B * 4), blk, 0, stream>>>(
      qbf, kbf, vhb, Opart, liPart, N);
  attn_combine<<<dim3(N / 128, 4, B), blk, 0, stream>>>(Opart, liPart, atb, N);

  // message (cols head-major-permuted to match atb)
  gemm128<<<dim3(N / 128, 2, B), blk, 0, stream>>>(
      wmb, biasb + 768, atb, atb, msb, nullptr, nullptr, 256, 256, 256, N, 0,
      nullptr, nullptr);

  // h = W1 @ [x; msg] + b1, with fused InstanceNorm stats (variant 4)
  gemm128<<<dim3(N / 128, 4, B), blk, 0, stream>>>(
      w1b, biasb + 1024, xb, msb, hb, nullptr, nullptr,
      512, 512, 256, N, 4, Ps, Ps2);

  // out = W2 @ normrelu(h) (variant 5: norm fused into X-staging; fp32 CHN)
  gemm128<<<dim3(N / 128, 2, B), blk, 0, stream>>>(
      w2b, biasb + 1536, hb, hb, out, nullptr, nullptr,
      256, 512, 512, N, 5, Ps, Ps2);
}